// Round 10
// baseline (99.337 us; speedup 1.0000x reference)
//
#include <hip/hip_runtime.h>
#include <hip/hip_bf16.h>

// Sparse self-attention == dense attention within each residue class (mod 4)
// + 7-wide window (duplicate entries => logit += 1.0 in log2 space)
// + OOB window slots adding exp2(0)=1 to the denominator
// + zero key n=1024 folded into the epilogue denominator.
// prep -> fused QKV GEMM (XCD-chunked) -> flash attn:
// BARRIER-FREE main loop: K/V fragments read directly from L2 (no LDS
// staging), 32x32 MFMA, swapped QK^T (q lane-local), P in-register,
// wave-level SPLIT-K (exact: fixed M=0), LDS used only for the reduction.

#define BATCH 2
#define LSEQ  4096
#define DMODEL 512
#define NH    8
#define DHEAD 64
#define NPAD  1088      // K/V row stride (valid rows 0..1023; tails never touched)
#define QSCALE 0.18033688011112042f   // 0.125 * log2(e)

typedef __bf16 bf16x8 __attribute__((ext_vector_type(8)));
typedef __attribute__((ext_vector_type(4))) float f32x4;
typedef __attribute__((ext_vector_type(16))) float f32x16;
typedef unsigned short u16;
typedef unsigned int u32;
typedef __attribute__((ext_vector_type(8))) u16 u16x8;
typedef __attribute__((ext_vector_type(4))) u16 u16x4;
typedef __attribute__((ext_vector_type(4))) u32 u32x4;

__device__ __forceinline__ u16 f2bf(float f) {
    u32 u = __float_as_uint(f);
    u += 0x7fffu + ((u >> 16) & 1u);   // RNE, finite inputs
    return (u16)(u >> 16);
}

__device__ __forceinline__ u32 cvtpk(float lo, float hi) {
    u32 d;
    asm("v_cvt_pk_bf16_f32 %0, %1, %2" : "=v"(d) : "v"(lo), "v"(hi));
    return d;
}

__device__ __forceinline__ void gload16(const u16* g, u16* l) {
    __builtin_amdgcn_global_load_lds(
        (const __attribute__((address_space(1))) u32*)(const void*)g,
        (__attribute__((address_space(3))) u32*)(void*)l, 16, 0, 0);
}

__device__ __forceinline__ f32x16 zero16() {
    f32x16 v;
    #pragma unroll
    for (int i = 0; i < 16; ++i) v[i] = 0.f;
    return v;
}

// ---------------------------------------------------------------------------
// prep: bid<2048: xb = bf16(x);  2048..2239: Wt[c][k] = bf16(W[k][c]) transposed
// ---------------------------------------------------------------------------
__global__ __launch_bounds__(256) void prep_kernel(
    const float* __restrict__ x,
    const float* __restrict__ Wq, const float* __restrict__ Wk, const float* __restrict__ Wv,
    u16* __restrict__ xb, u16* __restrict__ Wt)
{
    const int bid = blockIdx.x, tid = threadIdx.x;
    if (bid < 2048) {
        const size_t i0 = (size_t)bid * 2048 + (size_t)tid * 8;
        float4 a = *(const float4*)(x + i0);
        float4 b = *(const float4*)(x + i0 + 4);
        u16x8 o = { f2bf(a.x), f2bf(a.y), f2bf(a.z), f2bf(a.w),
                    f2bf(b.x), f2bf(b.y), f2bf(b.z), f2bf(b.w) };
        *(u16x8*)(xb + i0) = o;
    } else {
        const int wb  = bid - 2048;            // 0..191
        const int mat = wb >> 6;
        const int t   = wb & 63;
        const int k0  = (t >> 3) * 64, c0 = (t & 7) * 64;
        const float* W = (mat == 0) ? Wq : (mat == 1) ? Wk : Wv;
        __shared__ u16 Ws[64][72];             // [k][c]
        #pragma unroll
        for (int i = 0; i < 4; ++i) {
            const int chunk = i * 256 + tid;
            const int kr = chunk >> 4, c4 = (chunk & 15) * 4;
            float4 v = *(const float4*)(W + (size_t)(k0 + kr) * DMODEL + c0 + c4);
            u16x4 q = { f2bf(v.x), f2bf(v.y), f2bf(v.z), f2bf(v.w) };
            *(u16x4*)&Ws[kr][c4] = q;
        }
        __syncthreads();
        const int cc = tid >> 2, kq = (tid & 3) * 16;
        alignas(16) u16 tmp[16];
        #pragma unroll
        for (int kk = 0; kk < 16; ++kk) tmp[kk] = Ws[kq + kk][cc];
        u16* dst = Wt + (size_t)(mat * 512 + c0 + cc) * DMODEL + k0 + kq;
        *(u16x8*)dst       = *(const u16x8*)&tmp[0];
        *(u16x8*)(dst + 8) = *(const u16x8*)&tmp[8];
    }
}

// ---------------------------------------------------------------------------
// Fused QKV GEMM: C = xb(8192x512) * Wt^T(512x1536), BM=BN=128, BK=64, 4 waves.
// 1-D grid, XCD-chunked. nt 0-3 -> Q (scaled), 4-7 -> K, 8-11 -> V^T.
// ---------------------------------------------------------------------------
__global__ __launch_bounds__(256) void gemm_kernel(
    const u16* __restrict__ xb, const u16* __restrict__ Wt,
    u16* __restrict__ Qb, u16* __restrict__ Kb, u16* __restrict__ Vb)
{
    const int bid = blockIdx.x;
    const int xcd = bid & 7;
    const int j   = bid >> 3;            // 0..95
    const int mt  = xcd * 8 + (j / 12);  // 0..63
    const int nt  = j % 12;
    const int m0 = mt * 128;
    const int n0 = nt * 128;
    const int tid = threadIdx.x;
    const int w = tid >> 6, l = tid & 63, lr = l & 15, lh = l >> 4;
    const int wr = w >> 1, wc = w & 1;

    __shared__ u16 smem[16896];     // A:[0,8192) B:[8192,16384); V-retile 128*132
    u16* As = smem;
    u16* Bs = smem + 8192;

    f32x4 acc[4][4];
    const f32x4 fzero = {0.f, 0.f, 0.f, 0.f};
    #pragma unroll
    for (int mi = 0; mi < 4; ++mi)
        #pragma unroll
        for (int nj = 0; nj < 4; ++nj) acc[mi][nj] = fzero;

    for (int kt = 0; kt < 8; ++kt) {
        const int k0 = kt * 64;
        #pragma unroll
        for (int i = 0; i < 4; ++i) {
            const int cid = i * 256 + tid;
            const int row = cid >> 3, ch = cid & 7;
            const int sch = ch ^ (row & 7);
            u16* dstA = As + (i * 256 + w * 64) * 8;   // wave-uniform base
            u16* dstB = Bs + (i * 256 + w * 64) * 8;
            gload16(xb + (size_t)(m0 + row) * DMODEL + k0 + sch * 8, dstA);
            gload16(Wt + (size_t)(n0 + row) * DMODEL + k0 + sch * 8, dstB);
        }
        __syncthreads();

        #pragma unroll
        for (int kk = 0; kk < 2; ++kk) {
            const int cs = (kk * 4 + lh) ^ (lr & 7);   // swizzled chunk
            bf16x8 af[4], bfr[4];
            #pragma unroll
            for (int mi = 0; mi < 4; ++mi)
                af[mi] = *(const bf16x8*)(As + (wr * 64 + mi * 16 + lr) * 64 + cs * 8);
            #pragma unroll
            for (int nj = 0; nj < 4; ++nj)
                bfr[nj] = *(const bf16x8*)(Bs + (wc * 64 + nj * 16 + lr) * 64 + cs * 8);
            #pragma unroll
            for (int mi = 0; mi < 4; ++mi)
                #pragma unroll
                for (int nj = 0; nj < 4; ++nj)
                    acc[mi][nj] = __builtin_amdgcn_mfma_f32_16x16x32_bf16(af[mi], bfr[nj], acc[mi][nj], 0, 0, 0);
        }
        __syncthreads();
    }

    const int mat = nt >> 2;
    const int hp  = nt & 3;
    if (mat < 2) {
        u16* Ob = (mat == 0) ? Qb : Kb;
        const float osc = (mat == 0) ? QSCALE : 1.0f;
        #pragma unroll
        for (int mi = 0; mi < 4; ++mi) {
            const int gmb = m0 + wr * 64 + mi * 16 + lh * 4;
            const int b = gmb >> 12;
            #pragma unroll
            for (int rr = 0; rr < 4; ++rr) {
                const int t = (gmb + rr) & 4095;
                const int n = t >> 2, r = t & 3;
                #pragma unroll
                for (int nj = 0; nj < 4; ++nj) {
                    const int c  = wc * 64 + nj * 16 + lr;
                    const int h  = hp * 2 + (c >> 6);
                    const int dk = c & 63;
                    const size_t g = ((size_t)(b * NH + h)) * 4 + r;
                    Ob[(g * NPAD + n) * DHEAD + dk] = f2bf(acc[mi][nj][rr] * osc);
                }
            }
        }
    } else {
        // V: retile via LDS -> coalesced stores of V^T [g][dv][n]
        #pragma unroll
        for (int mi = 0; mi < 4; ++mi) {
            const int nrel = wr * 16 + mi * 4 + lh;
            #pragma unroll
            for (int nj = 0; nj < 4; ++nj) {
                const int c = wc * 64 + nj * 16 + lr;
                #pragma unroll
                for (int rr = 0; rr < 4; ++rr)
                    smem[c * 132 + rr * 32 + nrel] = f2bf(acc[mi][nj][rr]);
            }
        }
        __syncthreads();
        const int b  = m0 >> 12;
        const int nb = (m0 & 4095) >> 2;
        #pragma unroll
        for (int e = 0; e < 2; ++e) {
            const int chunk = e * 256 + tid;
            const int c = chunk & 127, r = chunk >> 7;
            const int h  = hp * 2 + (c >> 6);
            const int dv = c & 63;
            const size_t g = ((size_t)(b * NH + h)) * 4 + r;
            u16* dst = Vb + (g * DHEAD + dv) * NPAD + nb;
            const u16* src = smem + c * 132 + r * 32;
            alignas(16) u16 tmp[32];
            #pragma unroll
            for (int q8 = 0; q8 < 8; ++q8)
                *(u16x4*)&tmp[q8 * 4] = *(const u16x4*)(src + q8 * 4);
            #pragma unroll
            for (int q16 = 0; q16 < 4; ++q16)
                *(u16x8*)(dst + q16 * 8) = *(const u16x8*)&tmp[q16 * 8];
        }
    }
}

// ---------------------------------------------------------------------------
// Flash attention, barrier-free: block = 8 waves; waves 0-3 (kh=0) keys
// 0-511, waves 4-7 (kh=1) keys 512-1023, same 128 q-rows. K/V fragments
// read directly from global (XCD-L2-resident); no LDS staging, no in-loop
// barriers. Exact split-K (fixed M=0). Grid (64 g, 8 qblk).
// ---------------------------------------------------------------------------
__global__ __launch_bounds__(512, 4) void attn_kernel(
    const u16* __restrict__ Qb, const u16* __restrict__ Kb, const u16* __restrict__ Vb,
    float* __restrict__ out)
{
    const int g  = blockIdx.x;          // ((b*8+h)*4+r): blocks sharing g -> same XCD
    const int b  = g >> 5;
    const int h  = (g >> 2) & 7;
    const int r  = g & 3;
    const int q0 = blockIdx.y * 128;
    const int tid = threadIdx.x;
    const int w  = tid >> 6;            // 0..7
    const int wq = w & 3;               // q-subtile
    const int kh = w >> 2;              // key half
    const int l  = tid & 63;
    const int lr = l & 31;
    const int hi = l >> 5;

    const u16* Qg  = Qb + (size_t)g * NPAD * DHEAD;
    const u16* Kg  = Kb + (size_t)g * NPAD * DHEAD;
    const u16* Vtg = Vb + (size_t)g * DHEAD * NPAD;   // [dv][n]

    __shared__ float red[4 * 64 * 33];   // [wq][lane][33] O-partials
    __shared__ float redL[4 * 64];       // L partials

    // Q fragments: lane -> q-row q0 + wq*32 + lr, k-chunk c*16 + hi*8
    bf16x8 qa[4];
    {
        const u16* qrow = Qg + (size_t)(q0 + wq * 32 + lr) * DHEAD + hi * 8;
        qa[0] = *(const bf16x8*)(qrow);
        qa[1] = *(const bf16x8*)(qrow + 16);
        qa[2] = *(const bf16x8*)(qrow + 32);
        qa[3] = *(const bf16x8*)(qrow + 48);
    }

    f32x16 o0 = zero16(), o1 = zero16();
    float Lown = 0.f;
    const int qw0 = q0 + wq * 32;
    const int qg  = qw0 + lr;

    for (int mt = 0; mt < 8; ++mt) {
        const int mabs = kh * 512 + mt * 64;           // absolute key-tile base
        const u16* Kt = Kg  + (size_t)mabs * DHEAD;
        const u16* Vt = Vtg + mabs;

        // S^T = K Q^T : A = K-frag (rows=keys, direct from L2), B = Q-frag
        f32x16 sA = zero16(), sB = zero16();           // keys 0-31 / 32-63
        __builtin_amdgcn_s_setprio(1);
        #pragma unroll
        for (int c = 0; c < 4; ++c) {
            const int ch = c * 2 + hi;                 // 16B k-chunk 0..7
            bf16x8 kbA = *(const bf16x8*)(Kt + (size_t)lr * DHEAD + ch * 8);
            bf16x8 kbB = *(const bf16x8*)(Kt + (size_t)(32 + lr) * DHEAD + ch * 8);
            sA = __builtin_amdgcn_mfma_f32_32x32x16_bf16(kbA, qa[c], sA, 0, 0, 0);
            sB = __builtin_amdgcn_mfma_f32_32x32x16_bf16(kbB, qa[c], sB, 0, 0, 0);
        }
        __builtin_amdgcn_s_setprio(0);

        // softmax terms (fixed M=0, log2 space): p = exp2(s [+1 in window])
        const bool special = (mabs + 66 >= qw0) && (mabs <= qw0 + 34);
        if (!special) {
            #pragma unroll
            for (int reg = 0; reg < 16; ++reg) {
                sA[reg] = __builtin_amdgcn_exp2f(sA[reg]);
                sB[reg] = __builtin_amdgcn_exp2f(sB[reg]);
                Lown += sA[reg] + sB[reg];
            }
        } else {
            #pragma unroll
            for (int reg = 0; reg < 16; ++reg) {
                const int krel = (reg & 3) + 8 * (reg >> 2) + 4 * hi;
                {
                    const int dd = mabs + krel - qg;
                    float v = sA[reg];
                    if (dd >= -3 && dd <= 3) v += 1.0f;
                    sA[reg] = __builtin_amdgcn_exp2f(v);
                }
                {
                    const int dd = mabs + 32 + krel - qg;
                    float v = sB[reg];
                    if (dd >= -3 && dd <= 3) v += 1.0f;
                    sB[reg] = __builtin_amdgcn_exp2f(v);
                }
                Lown += sA[reg] + sB[reg];
            }
        }

        // pack P to bf16 pairs
        u32 pkA[8], pkB[8];
        #pragma unroll
        for (int r2 = 0; r2 < 8; ++r2) {
            pkA[r2] = cvtpk(sA[2 * r2], sA[2 * r2 + 1]);
            pkB[r2] = cvtpk(sB[2 * r2], sB[2 * r2 + 1]);
        }

        // PV: assemble A-frag (P) in-register, B = V-frag direct from L2
        __builtin_amdgcn_s_setprio(1);
        #pragma unroll
        for (int c = 0; c < 4; ++c) {
            const int c1 = c & 1;
            u32 p0, p1, p2, p3;
            if (c < 2) { p0 = pkA[4*c1]; p1 = pkA[4*c1+1]; p2 = pkA[4*c1+2]; p3 = pkA[4*c1+3]; }
            else       { p0 = pkB[4*c1]; p1 = pkB[4*c1+1]; p2 = pkB[4*c1+2]; p3 = pkB[4*c1+3]; }
            const u32 own0  = hi ? p2 : p0;
            const u32 own1  = hi ? p3 : p1;
            const u32 send0 = hi ? p0 : p2;
            const u32 send1 = hi ? p1 : p3;
            const u32 recv0 = (u32)__shfl_xor((int)send0, 32);
            const u32 recv1 = (u32)__shfl_xor((int)send1, 32);
            u32x4 paw;
            paw.x = hi ? recv0 : own0;
            paw.y = hi ? recv1 : own1;
            paw.z = hi ? own0  : recv0;
            paw.w = hi ? own1  : recv1;
            const bf16x8 pa = __builtin_bit_cast(bf16x8, paw);

            const int ch = c * 2 + hi;                 // key chunk 0..7
            bf16x8 vb0 = *(const bf16x8*)(Vt + (size_t)lr * NPAD + ch * 8);          // dv 0-31
            bf16x8 vb1 = *(const bf16x8*)(Vt + (size_t)(32 + lr) * NPAD + ch * 8);   // dv 32-63
            o0 = __builtin_amdgcn_mfma_f32_32x32x16_bf16(pa, vb0, o0, 0, 0, 0);
            o1 = __builtin_amdgcn_mfma_f32_32x32x16_bf16(pa, vb1, o1, 0, 0, 0);
        }
        __builtin_amdgcn_s_setprio(0);
    }

    // split-K reduction: kh=1 waves publish partials; kh=0 combine + store.
    if (kh == 1) {
        float* dst = red + ((size_t)wq * 64 + l) * 33;
        #pragma unroll
        for (int reg = 0; reg < 16; ++reg) {
            dst[reg]      = o0[reg];
            dst[16 + reg] = o1[reg];
        }
        redL[wq * 64 + l] = Lown;
    }
    __syncthreads();
    if (kh == 0) {
        const float* src = red + ((size_t)wq * 64 + l) * 33;
        #pragma unroll
        for (int reg = 0; reg < 16; ++reg) {
            o0[reg] += src[reg];
            o1[reg] += src[16 + reg];
        }
        Lown += redL[wq * 64 + l];

        const float Ltot = Lown + __shfl_xor(Lown, 32);
        const int coob = (qg < 3 ? 3 - qg : 0) + (qg > 1021 ? qg - 1021 : 0);
        const float inv = 1.0f / (Ltot + (float)(coob + 1 + (qg >= 1021 ? 1 : 0)));

        float iv[16];
        #pragma unroll
        for (int reg = 0; reg < 16; ++reg)
            iv[reg] = __shfl(inv, (reg & 3) + 8 * (reg >> 2) + 4 * hi);

        #pragma unroll
        for (int reg = 0; reg < 16; ++reg) {
            const int qrel = (reg & 3) + 8 * (reg >> 2) + 4 * hi;
            const int t = (q0 + wq * 32 + qrel) * 4 + r;
            float* orow = out + ((size_t)b * LSEQ + t) * DMODEL + h * DHEAD;
            orow[lr]      = o0[reg] * iv[reg];
            orow[32 + lr] = o1[reg] * iv[reg];
        }
    }
}

extern "C" void kernel_launch(void* const* d_in, const int* in_sizes, int n_in,
                              void* d_out, int out_size, void* d_ws, size_t ws_size,
                              hipStream_t stream) {
    const float* x  = (const float*)d_in[0];
    const float* Wq = (const float*)d_in[1];
    const float* Wk = (const float*)d_in[2];
    const float* Wv = (const float*)d_in[3];
    float* out = (float*)d_out;

    const size_t SZ = (size_t)BATCH * NH * 4 * NPAD * DHEAD;   // per-tensor elems
    u16* Qb = (u16*)d_ws;
    u16* Kb = Qb + SZ;
    u16* Vb = Kb + SZ;

    // scratch for bf16 x and transposed W lives in d_out (overwritten by attn)
    u16* xb = (u16*)d_out;                       // 8192*512 u16
    u16* Wt = xb + (size_t)8192 * 512;           // 1536*512 u16

    prep_kernel<<<2240, 256, 0, stream>>>(x, Wq, Wk, Wv, xb, Wt);

    gemm_kernel<<<768, 256, 0, stream>>>(xb, Wt, Qb, Kb, Vb);

    dim3 ga(64, 8);
    attn_kernel<<<ga, 512, 0, stream>>>(Qb, Kb, Vb, out);
}

// Round 11
// 71.299 us; speedup vs baseline: 1.3932x; 1.3932x over previous
//
#include <hip/hip_runtime.h>
#include <hip/hip_bf16.h>

// Sparse self-attention == dense attention within each residue class (mod 4)
// + 7-wide window (duplicate entries => logit += 1.0 in log2 space)
// + OOB window slots adding exp2(0)=1 to the denominator
// + zero key n=1024 folded into the epilogue denominator.
// prep (W transpose only) -> fused QKV GEMM (fp32 x converted in-kernel,
// XCD-chunked grid) -> flash attn (R6 structure: 16x16 MFMA, 8 waves/128q,
// gload_lds double-buffer, counted vmcnt, XCD-local grid).

#define BATCH 2
#define LSEQ  4096
#define DMODEL 512
#define NH    8
#define DHEAD 64
#define NPAD  1088      // K/V row stride (valid rows 0..1023; tails never touched)
#define QSCALE 0.18033688011112042f   // 0.125 * log2(e)

typedef __bf16 bf16x8 __attribute__((ext_vector_type(8)));
typedef __attribute__((ext_vector_type(4))) float f32x4;
typedef unsigned short u16;
typedef unsigned int u32;
typedef __attribute__((ext_vector_type(8))) u16 u16x8;
typedef __attribute__((ext_vector_type(4))) u16 u16x4;

__device__ __forceinline__ u16 f2bf(float f) {
    u32 u = __float_as_uint(f);
    u += 0x7fffu + ((u >> 16) & 1u);   // RNE, finite inputs
    return (u16)(u >> 16);
}

__device__ __forceinline__ u16 cvt_bf(float f) {
    __bf16 t = (__bf16)f;              // native v_cvt on gfx950
    return *(const u16*)&t;
}

__device__ __forceinline__ void gload16(const u16* g, u16* l) {
    __builtin_amdgcn_global_load_lds(
        (const __attribute__((address_space(1))) u32*)(const void*)g,
        (__attribute__((address_space(3))) u32*)(void*)l, 16, 0, 0);
}

// ---------------------------------------------------------------------------
// prep: Wt[c][k] = bf16(W_mat[k][col]) transposed; c = mat*512 + col.
// 192 blocks, one 64x64 tile each.
// ---------------------------------------------------------------------------
__global__ __launch_bounds__(256) void prep_kernel(
    const float* __restrict__ Wq, const float* __restrict__ Wk, const float* __restrict__ Wv,
    u16* __restrict__ Wt)
{
    const int wb  = blockIdx.x;            // 0..191
    const int tid = threadIdx.x;
    const int mat = wb >> 6;
    const int t   = wb & 63;
    const int k0  = (t >> 3) * 64, c0 = (t & 7) * 64;
    const float* W = (mat == 0) ? Wq : (mat == 1) ? Wk : Wv;
    __shared__ u16 Ws[64][72];             // [k][c]
    #pragma unroll
    for (int i = 0; i < 4; ++i) {
        const int chunk = i * 256 + tid;
        const int kr = chunk >> 4, c4 = (chunk & 15) * 4;
        float4 v = *(const float4*)(W + (size_t)(k0 + kr) * DMODEL + c0 + c4);
        u16x4 q = { f2bf(v.x), f2bf(v.y), f2bf(v.z), f2bf(v.w) };
        *(u16x4*)&Ws[kr][c4] = q;
    }
    __syncthreads();
    const int cc = tid >> 2, kq = (tid & 3) * 16;
    alignas(16) u16 tmp[16];
    #pragma unroll
    for (int kk = 0; kk < 16; ++kk) tmp[kk] = Ws[kq + kk][cc];
    u16* dst = Wt + (size_t)(mat * 512 + c0 + cc) * DMODEL + k0 + kq;
    *(u16x8*)dst       = *(const u16x8*)&tmp[0];
    *(u16x8*)(dst + 8) = *(const u16x8*)&tmp[8];
}

// ---------------------------------------------------------------------------
// Fused QKV GEMM: C = x(8192x512, fp32) * Wt^T(512x1536), BM=BN=128, BK=64,
// 4 waves. A staged by reg-convert (fp32->bf16, same swizzled LDS layout),
// B staged via global_load_lds. 1-D grid, XCD-chunked.
// nt 0-3 -> Q (scaled), 4-7 -> K, 8-11 -> V (written transposed via LDS).
// ---------------------------------------------------------------------------
__global__ __launch_bounds__(256) void gemm_kernel(
    const float* __restrict__ x, const u16* __restrict__ Wt,
    u16* __restrict__ Qb, u16* __restrict__ Kb, u16* __restrict__ Vb)
{
    const int bid = blockIdx.x;
    const int xcd = bid & 7;
    const int j   = bid >> 3;            // 0..95
    const int mt  = xcd * 8 + (j / 12);  // 0..63
    const int nt  = j % 12;
    const int m0 = mt * 128;
    const int n0 = nt * 128;
    const int tid = threadIdx.x;
    const int w = tid >> 6, l = tid & 63, lr = l & 15, lh = l >> 4;
    const int wr = w >> 1, wc = w & 1;

    __shared__ u16 smem[16896];     // A:[0,8192) B:[8192,16384); V-retile 128*132
    u16* As = smem;
    u16* Bs = smem + 8192;

    f32x4 acc[4][4];
    const f32x4 fzero = {0.f, 0.f, 0.f, 0.f};
    #pragma unroll
    for (int mi = 0; mi < 4; ++mi)
        #pragma unroll
        for (int nj = 0; nj < 4; ++nj) acc[mi][nj] = fzero;

    for (int kt = 0; kt < 8; ++kt) {
        const int k0 = kt * 64;
        #pragma unroll
        for (int i = 0; i < 4; ++i) {
            const int cid = i * 256 + tid;
            const int row = cid >> 3, ch = cid & 7;
            const int sch = ch ^ (row & 7);
            // B: async gload_lds (wave-uniform dest base + lane*16)
            gload16(Wt + (size_t)(n0 + row) * DMODEL + k0 + sch * 8,
                    Bs + (i * 256 + w * 64) * 8);
            // A: reg-staged fp32 -> bf16 into the SAME swizzled layout
            const float* srcA = x + (size_t)(m0 + row) * DMODEL + k0 + sch * 8;
            float4 a4 = *(const float4*)srcA;
            float4 b4 = *(const float4*)(srcA + 4);
            u16x8 o8 = { f2bf(a4.x), f2bf(a4.y), f2bf(a4.z), f2bf(a4.w),
                         f2bf(b4.x), f2bf(b4.y), f2bf(b4.z), f2bf(b4.w) };
            *(u16x8*)(As + (size_t)cid * 8) = o8;
        }
        __syncthreads();

        #pragma unroll
        for (int kk = 0; kk < 2; ++kk) {
            const int cs = (kk * 4 + lh) ^ (lr & 7);   // swizzled chunk
            bf16x8 af[4], bfr[4];
            #pragma unroll
            for (int mi = 0; mi < 4; ++mi)
                af[mi] = *(const bf16x8*)(As + (wr * 64 + mi * 16 + lr) * 64 + cs * 8);
            #pragma unroll
            for (int nj = 0; nj < 4; ++nj)
                bfr[nj] = *(const bf16x8*)(Bs + (wc * 64 + nj * 16 + lr) * 64 + cs * 8);
            #pragma unroll
            for (int mi = 0; mi < 4; ++mi)
                #pragma unroll
                for (int nj = 0; nj < 4; ++nj)
                    acc[mi][nj] = __builtin_amdgcn_mfma_f32_16x16x32_bf16(af[mi], bfr[nj], acc[mi][nj], 0, 0, 0);
        }
        __syncthreads();
    }

    const int mat = nt >> 2;
    const int hp  = nt & 3;
    if (mat < 2) {
        u16* Ob = (mat == 0) ? Qb : Kb;
        const float osc = (mat == 0) ? QSCALE : 1.0f;
        #pragma unroll
        for (int mi = 0; mi < 4; ++mi) {
            const int gmb = m0 + wr * 64 + mi * 16 + lh * 4;
            const int b = gmb >> 12;
            #pragma unroll
            for (int rr = 0; rr < 4; ++rr) {
                const int t = (gmb + rr) & 4095;
                const int n = t >> 2, r = t & 3;
                #pragma unroll
                for (int nj = 0; nj < 4; ++nj) {
                    const int c  = wc * 64 + nj * 16 + lr;
                    const int h  = hp * 2 + (c >> 6);
                    const int dk = c & 63;
                    const size_t g = ((size_t)(b * NH + h)) * 4 + r;
                    Ob[(g * NPAD + n) * DHEAD + dk] = f2bf(acc[mi][nj][rr] * osc);
                }
            }
        }
    } else {
        // V: retile via LDS -> coalesced stores of V^T [g][dv][n]
        #pragma unroll
        for (int mi = 0; mi < 4; ++mi) {
            const int nrel = wr * 16 + mi * 4 + lh;
            #pragma unroll
            for (int nj = 0; nj < 4; ++nj) {
                const int c = wc * 64 + nj * 16 + lr;
                #pragma unroll
                for (int rr = 0; rr < 4; ++rr)
                    smem[c * 132 + rr * 32 + nrel] = f2bf(acc[mi][nj][rr]);
            }
        }
        __syncthreads();
        const int b  = m0 >> 12;
        const int nb = (m0 & 4095) >> 2;
        #pragma unroll
        for (int e = 0; e < 2; ++e) {
            const int chunk = e * 256 + tid;
            const int c = chunk & 127, r = chunk >> 7;
            const int h  = hp * 2 + (c >> 6);
            const int dv = c & 63;
            const size_t g = ((size_t)(b * NH + h)) * 4 + r;
            u16* dst = Vb + (g * DHEAD + dv) * NPAD + nb;
            const u16* src = smem + c * 132 + r * 32;
            alignas(16) u16 tmp[32];
            #pragma unroll
            for (int q8 = 0; q8 < 8; ++q8)
                *(u16x4*)&tmp[q8 * 4] = *(const u16x4*)(src + q8 * 4);
            #pragma unroll
            for (int q16 = 0; q16 < 4; ++q16)
                *(u16x8*)(dst + q16 * 8) = *(const u16x8*)&tmp[q16 * 8];
        }
    }
}

// ---------------------------------------------------------------------------
// Flash attention per (b,h,r): 128 queries/block (8 waves x 16 rows),
// 16 key tiles of 64 (zero key n=1024 folded into epilogue).  [R6 verbatim]
// ---------------------------------------------------------------------------
__global__ __launch_bounds__(512) void attn_kernel(
    const u16* __restrict__ Qb, const u16* __restrict__ Kb, const u16* __restrict__ Vb,
    float* __restrict__ out)
{
    const int g  = blockIdx.x;          // ((b*8+h)*4+r): blocks sharing g -> same XCD
    const int b  = g >> 5;
    const int h  = (g >> 2) & 7;
    const int r  = g & 3;
    const int q0 = blockIdx.y * 128;
    const int tid = threadIdx.x;
    const int w  = tid >> 6;            // 0..7
    const int l  = tid & 63;
    const int lr = l & 15, lh = l >> 4;

    const u16* Qg  = Qb + (size_t)g * NPAD * DHEAD;
    const u16* Kg  = Kb + (size_t)g * NPAD * DHEAD;
    const u16* Vtg = Vb + (size_t)g * DHEAD * NPAD;   // [dv][n]

    __shared__ u16 KV[2][2][4096];   // [buf][K/V][64 rows][8 slots][8 u16]
    __shared__ u16 Ps[8][16][68];    // per-wave P tile [qrow][m]

    // staging: thread -> (row = tid>>3, slot = tid&7), source chunk XOR-swizzled
    const int srow = tid >> 3;
    const int ssch = (tid & 7) ^ (srow & 7);
    const u16* ksrc0 = Kg  + (size_t)srow * DHEAD + ssch * 8;
    const u16* vsrc0 = Vtg + (size_t)srow * NPAD  + ssch * 8;

    bf16x8 qa[2];
    {
        const u16* qrow = Qg + (size_t)(q0 + w * 16 + lr) * DHEAD;
        qa[0] = *(const bf16x8*)(qrow + lh * 8);
        qa[1] = *(const bf16x8*)(qrow + 32 + lh * 8);
    }

    const f32x4 fzero = {0.f, 0.f, 0.f, 0.f};
    f32x4 o[4];
    #pragma unroll
    for (int j = 0; j < 4; ++j) o[j] = fzero;
    float Lpart[4] = {0.f, 0.f, 0.f, 0.f};

    const int qw0 = q0 + w * 16;

    // prologue: stage tile 0 into buf 0
    gload16(ksrc0, &KV[0][0][w * 512]);
    gload16(vsrc0, &KV[0][1][w * 512]);

    for (int mt = 0; mt < 16; ++mt) {
        const int cur = mt & 1;
        if (mt < 15) {
            gload16(ksrc0 + (size_t)(mt + 1) * 64 * DHEAD, &KV[cur ^ 1][0][w * 512]);
            gload16(vsrc0 + (mt + 1) * 64,                 &KV[cur ^ 1][1][w * 512]);
            asm volatile("s_waitcnt vmcnt(2)" ::: "memory");
        } else {
            asm volatile("s_waitcnt vmcnt(0)" ::: "memory");
        }
        __builtin_amdgcn_s_barrier();

        const u16* Kbuf = KV[cur][0];
        const u16* Vbuf = KV[cur][1];

        // S = Q K^T (wave: 16 x 64), logits already in log2 space
        f32x4 s[4];
        __builtin_amdgcn_s_setprio(1);
        #pragma unroll
        for (int ni = 0; ni < 4; ++ni) {
            const int rbase = (ni * 16 + lr) * 8;
            const int sl0 = lh ^ (lr & 7), sl1 = (4 + lh) ^ (lr & 7);
            bf16x8 kb0 = *(const bf16x8*)(Kbuf + (rbase + sl0) * 8);
            bf16x8 kb1 = *(const bf16x8*)(Kbuf + (rbase + sl1) * 8);
            f32x4 t = __builtin_amdgcn_mfma_f32_16x16x32_bf16(qa[0], kb0, fzero, 0, 0, 0);
            s[ni] = __builtin_amdgcn_mfma_f32_16x16x32_bf16(qa[1], kb1, t, 0, 0, 0);
        }
        __builtin_amdgcn_s_setprio(0);

        const int m0 = mt * 64;
        const bool special = (m0 + 66 >= qw0) && (m0 <= qw0 + 18);
        if (!special) {
            #pragma unroll
            for (int ni = 0; ni < 4; ++ni) {
                #pragma unroll
                for (int rr = 0; rr < 4; ++rr) {
                    const float p = __builtin_amdgcn_exp2f(s[ni][rr]);
                    Lpart[rr] += p;
                    Ps[w][lh * 4 + rr][ni * 16 + lr] = cvt_bf(p);
                }
            }
        } else {
            #pragma unroll
            for (int ni = 0; ni < 4; ++ni) {
                const int mg = m0 + ni * 16 + lr;
                #pragma unroll
                for (int rr = 0; rr < 4; ++rr) {
                    const int qg = qw0 + lh * 4 + rr;
                    float v = s[ni][rr];
                    const int dd = mg - qg;
                    if (dd >= -3 && dd <= 3) v += 1.0f;    // window doubling
                    const float p = __builtin_amdgcn_exp2f(v);
                    Lpart[rr] += p;
                    Ps[w][lh * 4 + rr][ni * 16 + lr] = cvt_bf(p);
                }
            }
        }

        // O += P V (Ps per-wave; Vbuf swizzled slots)
        __builtin_amdgcn_s_setprio(1);
        #pragma unroll
        for (int kk = 0; kk < 2; ++kk) {
            const int slot = (kk * 4 + lh) ^ (lr & 7);
            bf16x8 pa = *(const bf16x8*)&Ps[w][lr][kk * 32 + lh * 8];
            #pragma unroll
            for (int j = 0; j < 4; ++j) {
                bf16x8 vb = *(const bf16x8*)(Vbuf + ((j * 16 + lr) * 8 + slot) * 8);
                o[j] = __builtin_amdgcn_mfma_f32_16x16x32_bf16(pa, vb, o[j], 0, 0, 0);
            }
        }
        __builtin_amdgcn_s_setprio(0);
        __syncthreads();   // all waves done reading buf before next-iter writes
    }

    // epilogue: dense zero-key (+1), its window double (q>=1021 ? +1), OOB (+coob)
    #pragma unroll
    for (int rr = 0; rr < 4; ++rr) {
        float s_ = Lpart[rr];
        #pragma unroll
        for (int off = 1; off < 16; off <<= 1)
            s_ += __shfl_xor(s_, off, 16);
        const int qg = qw0 + lh * 4 + rr;
        const int coob = (qg < 3 ? 3 - qg : 0) + (qg > 1021 ? qg - 1021 : 0);
        const float extra = (float)(coob + 1 + (qg >= 1021 ? 1 : 0));
        const float inv = 1.0f / (s_ + extra);
        const int t = qg * 4 + r;
        float* orow = out + ((size_t)b * LSEQ + t) * DMODEL + h * DHEAD;
        #pragma unroll
        for (int j = 0; j < 4; ++j)
            orow[j * 16 + lr] = o[j][rr] * inv;
    }
}

extern "C" void kernel_launch(void* const* d_in, const int* in_sizes, int n_in,
                              void* d_out, int out_size, void* d_ws, size_t ws_size,
                              hipStream_t stream) {
    const float* x  = (const float*)d_in[0];
    const float* Wq = (const float*)d_in[1];
    const float* Wk = (const float*)d_in[2];
    const float* Wv = (const float*)d_in[3];
    float* out = (float*)d_out;

    const size_t SZ = (size_t)BATCH * NH * 4 * NPAD * DHEAD;   // per-tensor elems
    u16* Qb = (u16*)d_ws;
    u16* Kb = Qb + SZ;
    u16* Vb = Kb + SZ;

    // transposed-W scratch lives in d_out (fully overwritten by attn later)
    u16* Wt = (u16*)d_out;                       // 1536*512 u16 = 1.5 MB

    prep_kernel<<<192, 256, 0, stream>>>(Wq, Wk, Wv, Wt);

    gemm_kernel<<<768, 256, 0, stream>>>(x, Wt, Qb, Kb, Vb);

    dim3 ga(64, 8);
    attn_kernel<<<ga, 512, 0, stream>>>(Qb, Kb, Vb, out);
}

// Round 12
// 68.995 us; speedup vs baseline: 1.4398x; 1.0334x over previous
//
#include <hip/hip_runtime.h>
#include <hip/hip_bf16.h>

// Sparse self-attention == dense attention within each residue class (mod 4)
// + 7-wide window (duplicate entries => logit += 1.0 in log2 space)
// + OOB window slots adding exp2(0)=1 to the denominator
// + zero key n=1024 folded into the epilogue denominator.
// prep (x->bf16, W transpose) -> fused QKV GEMM (XCD-chunked, R6) ->
// flash attn: 16x16 MFMA with SWAPPED QK (q lane-local), P in-register via
// cvt_pk + shfl exchange, triple-buffered K/V, ONE barrier per tile.

#define BATCH 2
#define LSEQ  4096
#define DMODEL 512
#define NH    8
#define DHEAD 64
#define NPAD  1088      // K/V row stride (valid rows 0..1023; tails never touched)
#define QSCALE 0.18033688011112042f   // 0.125 * log2(e)

typedef __bf16 bf16x8 __attribute__((ext_vector_type(8)));
typedef __attribute__((ext_vector_type(4))) float f32x4;
typedef unsigned short u16;
typedef unsigned int u32;
typedef __attribute__((ext_vector_type(8))) u16 u16x8;
typedef __attribute__((ext_vector_type(4))) u16 u16x4;
typedef __attribute__((ext_vector_type(4))) u32 u32x4;

__device__ __forceinline__ u16 f2bf(float f) {
    u32 u = __float_as_uint(f);
    u += 0x7fffu + ((u >> 16) & 1u);   // RNE, finite inputs
    return (u16)(u >> 16);
}

__device__ __forceinline__ u32 cvtpk(float lo, float hi) {
    u32 d;
    asm("v_cvt_pk_bf16_f32 %0, %1, %2" : "=v"(d) : "v"(lo), "v"(hi));
    return d;
}

__device__ __forceinline__ void gload16(const u16* g, u16* l) {
    __builtin_amdgcn_global_load_lds(
        (const __attribute__((address_space(1))) u32*)(const void*)g,
        (__attribute__((address_space(3))) u32*)(void*)l, 16, 0, 0);
}

// ---------------------------------------------------------------------------
// prep: bid<2048: xb = bf16(x);  2048..2239: Wt[c][k] = bf16(W[k][c]) transposed
// ---------------------------------------------------------------------------
__global__ __launch_bounds__(256) void prep_kernel(
    const float* __restrict__ x,
    const float* __restrict__ Wq, const float* __restrict__ Wk, const float* __restrict__ Wv,
    u16* __restrict__ xb, u16* __restrict__ Wt)
{
    const int bid = blockIdx.x, tid = threadIdx.x;
    if (bid < 2048) {
        const size_t i0 = (size_t)bid * 2048 + (size_t)tid * 8;
        float4 a = *(const float4*)(x + i0);
        float4 b = *(const float4*)(x + i0 + 4);
        u16x8 o = { f2bf(a.x), f2bf(a.y), f2bf(a.z), f2bf(a.w),
                    f2bf(b.x), f2bf(b.y), f2bf(b.z), f2bf(b.w) };
        *(u16x8*)(xb + i0) = o;
    } else {
        const int wb  = bid - 2048;            // 0..191
        const int mat = wb >> 6;
        const int t   = wb & 63;
        const int k0  = (t >> 3) * 64, c0 = (t & 7) * 64;
        const float* W = (mat == 0) ? Wq : (mat == 1) ? Wk : Wv;
        __shared__ u16 Ws[64][72];             // [k][c]
        #pragma unroll
        for (int i = 0; i < 4; ++i) {
            const int chunk = i * 256 + tid;
            const int kr = chunk >> 4, c4 = (chunk & 15) * 4;
            float4 v = *(const float4*)(W + (size_t)(k0 + kr) * DMODEL + c0 + c4);
            u16x4 q = { f2bf(v.x), f2bf(v.y), f2bf(v.z), f2bf(v.w) };
            *(u16x4*)&Ws[kr][c4] = q;
        }
        __syncthreads();
        const int cc = tid >> 2, kq = (tid & 3) * 16;
        alignas(16) u16 tmp[16];
        #pragma unroll
        for (int kk = 0; kk < 16; ++kk) tmp[kk] = Ws[kq + kk][cc];
        u16* dst = Wt + (size_t)(mat * 512 + c0 + cc) * DMODEL + k0 + kq;
        *(u16x8*)dst       = *(const u16x8*)&tmp[0];
        *(u16x8*)(dst + 8) = *(const u16x8*)&tmp[8];
    }
}

// ---------------------------------------------------------------------------
// Fused QKV GEMM: C = xb(8192x512) * Wt^T(512x1536), BM=BN=128, BK=64, 4 waves.
// 1-D grid, XCD-chunked. nt 0-3 -> Q (scaled), 4-7 -> K, 8-11 -> V^T.  [R6]
// ---------------------------------------------------------------------------
__global__ __launch_bounds__(256) void gemm_kernel(
    const u16* __restrict__ xb, const u16* __restrict__ Wt,
    u16* __restrict__ Qb, u16* __restrict__ Kb, u16* __restrict__ Vb)
{
    const int bid = blockIdx.x;
    const int xcd = bid & 7;
    const int j   = bid >> 3;            // 0..95
    const int mt  = xcd * 8 + (j / 12);  // 0..63
    const int nt  = j % 12;
    const int m0 = mt * 128;
    const int n0 = nt * 128;
    const int tid = threadIdx.x;
    const int w = tid >> 6, l = tid & 63, lr = l & 15, lh = l >> 4;
    const int wr = w >> 1, wc = w & 1;

    __shared__ u16 smem[16896];     // A:[0,8192) B:[8192,16384); V-retile 128*132
    u16* As = smem;
    u16* Bs = smem + 8192;

    f32x4 acc[4][4];
    const f32x4 fzero = {0.f, 0.f, 0.f, 0.f};
    #pragma unroll
    for (int mi = 0; mi < 4; ++mi)
        #pragma unroll
        for (int nj = 0; nj < 4; ++nj) acc[mi][nj] = fzero;

    for (int kt = 0; kt < 8; ++kt) {
        const int k0 = kt * 64;
        #pragma unroll
        for (int i = 0; i < 4; ++i) {
            const int cid = i * 256 + tid;
            const int row = cid >> 3, ch = cid & 7;
            const int sch = ch ^ (row & 7);
            u16* dstA = As + (i * 256 + w * 64) * 8;   // wave-uniform base
            u16* dstB = Bs + (i * 256 + w * 64) * 8;
            gload16(xb + (size_t)(m0 + row) * DMODEL + k0 + sch * 8, dstA);
            gload16(Wt + (size_t)(n0 + row) * DMODEL + k0 + sch * 8, dstB);
        }
        __syncthreads();

        #pragma unroll
        for (int kk = 0; kk < 2; ++kk) {
            const int cs = (kk * 4 + lh) ^ (lr & 7);   // swizzled chunk
            bf16x8 af[4], bfr[4];
            #pragma unroll
            for (int mi = 0; mi < 4; ++mi)
                af[mi] = *(const bf16x8*)(As + (wr * 64 + mi * 16 + lr) * 64 + cs * 8);
            #pragma unroll
            for (int nj = 0; nj < 4; ++nj)
                bfr[nj] = *(const bf16x8*)(Bs + (wc * 64 + nj * 16 + lr) * 64 + cs * 8);
            #pragma unroll
            for (int mi = 0; mi < 4; ++mi)
                #pragma unroll
                for (int nj = 0; nj < 4; ++nj)
                    acc[mi][nj] = __builtin_amdgcn_mfma_f32_16x16x32_bf16(af[mi], bfr[nj], acc[mi][nj], 0, 0, 0);
        }
        __syncthreads();
    }

    const int mat = nt >> 2;
    const int hp  = nt & 3;
    if (mat < 2) {
        u16* Ob = (mat == 0) ? Qb : Kb;
        const float osc = (mat == 0) ? QSCALE : 1.0f;
        #pragma unroll
        for (int mi = 0; mi < 4; ++mi) {
            const int gmb = m0 + wr * 64 + mi * 16 + lh * 4;
            const int b = gmb >> 12;
            #pragma unroll
            for (int rr = 0; rr < 4; ++rr) {
                const int t = (gmb + rr) & 4095;
                const int n = t >> 2, r = t & 3;
                #pragma unroll
                for (int nj = 0; nj < 4; ++nj) {
                    const int c  = wc * 64 + nj * 16 + lr;
                    const int h  = hp * 2 + (c >> 6);
                    const int dk = c & 63;
                    const size_t g = ((size_t)(b * NH + h)) * 4 + r;
                    Ob[(g * NPAD + n) * DHEAD + dk] = f2bf(acc[mi][nj][rr] * osc);
                }
            }
        }
    } else {
        // V: retile via LDS -> coalesced stores of V^T [g][dv][n]
        #pragma unroll
        for (int mi = 0; mi < 4; ++mi) {
            const int nrel = wr * 16 + mi * 4 + lh;
            #pragma unroll
            for (int nj = 0; nj < 4; ++nj) {
                const int c = wc * 64 + nj * 16 + lr;
                #pragma unroll
                for (int rr = 0; rr < 4; ++rr)
                    smem[c * 132 + rr * 32 + nrel] = f2bf(acc[mi][nj][rr]);
            }
        }
        __syncthreads();
        const int b  = m0 >> 12;
        const int nb = (m0 & 4095) >> 2;
        #pragma unroll
        for (int e = 0; e < 2; ++e) {
            const int chunk = e * 256 + tid;
            const int c = chunk & 127, r = chunk >> 7;
            const int h  = hp * 2 + (c >> 6);
            const int dv = c & 63;
            const size_t g = ((size_t)(b * NH + h)) * 4 + r;
            u16* dst = Vb + (g * DHEAD + dv) * NPAD + nb;
            const u16* src = smem + c * 132 + r * 32;
            alignas(16) u16 tmp[32];
            #pragma unroll
            for (int q8 = 0; q8 < 8; ++q8)
                *(u16x4*)&tmp[q8 * 4] = *(const u16x4*)(src + q8 * 4);
            #pragma unroll
            for (int q16 = 0; q16 < 4; ++q16)
                *(u16x8*)(dst + q16 * 8) = *(const u16x8*)&tmp[q16 * 8];
        }
    }
}

// ---------------------------------------------------------------------------
// Flash attention per (b,h,r): 128 queries/block (8 waves x 16 q-rows),
// SWAPPED QK (A=K, B=Q => q = lane&15), P in-register, triple-buffered K/V,
// single barrier per tile, 2-deep prefetch at steady vmcnt(2).
// ---------------------------------------------------------------------------
__global__ __launch_bounds__(512, 4) void attn_kernel(
    const u16* __restrict__ Qb, const u16* __restrict__ Kb, const u16* __restrict__ Vb,
    float* __restrict__ out)
{
    const int g  = blockIdx.x;          // ((b*8+h)*4+r): blocks sharing g -> same XCD
    const int b  = g >> 5;
    const int h  = (g >> 2) & 7;
    const int r  = g & 3;
    const int q0 = blockIdx.y * 128;
    const int tid = threadIdx.x;
    const int w  = tid >> 6;            // 0..7
    const int l  = tid & 63;
    const int lr = l & 15, lh = l >> 4;

    const u16* Qg  = Qb + (size_t)g * NPAD * DHEAD;
    const u16* Kg  = Kb + (size_t)g * NPAD * DHEAD;
    const u16* Vtg = Vb + (size_t)g * DHEAD * NPAD;   // [dv][n]

    __shared__ u16 KV[3][2][4096];   // [buf][K/V][64 rows][8 slots][8 u16]

    // staging: thread -> (row = tid>>3, slot = tid&7), source chunk XOR-swizzled
    const int srow = tid >> 3;
    const int ssch = (tid & 7) ^ (srow & 7);
    const u16* ksrc0 = Kg  + (size_t)srow * DHEAD + ssch * 8;
    const u16* vsrc0 = Vtg + (size_t)srow * NPAD  + ssch * 8;

    // Q fragments (used as MFMA B operand): lane holds Q[q=qw0+lr][k=lh*8+j]
    bf16x8 qa[2];
    {
        const u16* qrow = Qg + (size_t)(q0 + w * 16 + lr) * DHEAD;
        qa[0] = *(const bf16x8*)(qrow + lh * 8);
        qa[1] = *(const bf16x8*)(qrow + 32 + lh * 8);
    }

    const f32x4 fzero = {0.f, 0.f, 0.f, 0.f};
    f32x4 o[4];                          // o[dj]: D[dv=dj*16+lh*4+rr][q=lr]
    #pragma unroll
    for (int j = 0; j < 4; ++j) o[j] = fzero;
    float Lown = 0.f;

    const int qw0 = q0 + w * 16;
    const int qg  = qw0 + lr;            // this lane's q-row

    // prologue: stage tiles 0,1 into bufs 0,1
    gload16(ksrc0,              &KV[0][0][w * 512]);
    gload16(vsrc0,              &KV[0][1][w * 512]);
    gload16(ksrc0 + 64 * DHEAD, &KV[1][0][w * 512]);
    gload16(vsrc0 + 64,         &KV[1][1][w * 512]);

    for (int mt = 0; mt < 16; ++mt) {
        if (mt < 15) asm volatile("s_waitcnt vmcnt(2)" ::: "memory");
        else         asm volatile("s_waitcnt vmcnt(0)" ::: "memory");
        __builtin_amdgcn_s_barrier();
        // issue tile mt+2 AFTER the barrier (WAR-safe vs readers of tile mt-1)
        if (mt < 14) {
            const int nb = (mt + 2) % 3;
            gload16(ksrc0 + (size_t)(mt + 2) * 64 * DHEAD, &KV[nb][0][w * 512]);
            gload16(vsrc0 + (mt + 2) * 64,                 &KV[nb][1][w * 512]);
        }

        const u16* Kbuf = KV[mt % 3][0];
        const u16* Vbuf = KV[mt % 3][1];

        // S^T = K Q^T: A = K (rows = keys), B = Q (cols = q)
        // s[ni]: D[key = mt*64 + ni*16 + lh*4 + rr][q = lr]
        f32x4 s[4];
        __builtin_amdgcn_s_setprio(1);
        #pragma unroll
        for (int ni = 0; ni < 4; ++ni) {
            const int rbase = (ni * 16 + lr) * 8;
            const int sl0 = lh ^ (lr & 7), sl1 = (4 + lh) ^ (lr & 7);
            bf16x8 kb0 = *(const bf16x8*)(Kbuf + (rbase + sl0) * 8);
            bf16x8 kb1 = *(const bf16x8*)(Kbuf + (rbase + sl1) * 8);
            f32x4 t = __builtin_amdgcn_mfma_f32_16x16x32_bf16(kb0, qa[0], fzero, 0, 0, 0);
            s[ni] = __builtin_amdgcn_mfma_f32_16x16x32_bf16(kb1, qa[1], t, 0, 0, 0);
        }
        __builtin_amdgcn_s_setprio(0);

        // softmax (fixed M=0, log2 space) — fully per-lane (q = qg)
        const int m0 = mt * 64;
        const bool special = (m0 + 66 >= qw0) && (m0 <= qw0 + 18);
        if (!special) {
            #pragma unroll
            for (int ni = 0; ni < 4; ++ni)
                #pragma unroll
                for (int rr = 0; rr < 4; ++rr) {
                    const float p = __builtin_amdgcn_exp2f(s[ni][rr]);
                    s[ni][rr] = p;
                    Lown += p;
                }
        } else {
            #pragma unroll
            for (int ni = 0; ni < 4; ++ni)
                #pragma unroll
                for (int rr = 0; rr < 4; ++rr) {
                    const int dd = m0 + ni * 16 + lh * 4 + rr - qg;
                    float v = s[ni][rr];
                    if (dd >= -3 && dd <= 3) v += 1.0f;    // window doubling
                    const float p = __builtin_amdgcn_exp2f(v);
                    s[ni][rr] = p;
                    Lown += p;
                }
        }

        // pack: pk[ni][wd] = bf16 pair (keys ni*16+lh*4 + wd*2 + {0,1})
        u32 pk[4][2];
        #pragma unroll
        for (int ni = 0; ni < 4; ++ni) {
            pk[ni][0] = cvtpk(s[ni][0], s[ni][1]);
            pk[ni][1] = cvtpk(s[ni][2], s[ni][3]);
        }

        // PV: O^T = V^T P^T.  A = V^T (rows = dv), B = P (rows = q).
        // B-frag word j2 (keys kk*32 + lh*8 + 2j2 + {0,1}) comes from lane
        // ((lh&1)*2 + (j2>>1))*16 + lr, word j2&1, block 2kk + (lh>>1).
        __builtin_amdgcn_s_setprio(1);
        #pragma unroll
        for (int kk = 0; kk < 2; ++kk) {
            u32 wd[4];
            #pragma unroll
            for (int j2 = 0; j2 < 4; ++j2) {
                const int srcl = ((lh & 1) * 2 + (j2 >> 1)) * 16 + lr;
                const u32 a0 = (u32)__shfl((int)pk[2 * kk + 0][j2 & 1], srcl);
                const u32 a1 = (u32)__shfl((int)pk[2 * kk + 1][j2 & 1], srcl);
                wd[j2] = (lh >= 2) ? a1 : a0;
            }
            u32x4 paw = { wd[0], wd[1], wd[2], wd[3] };
            const bf16x8 pb = __builtin_bit_cast(bf16x8, paw);

            const int slot = (kk * 4 + lh) ^ (lr & 7);
            #pragma unroll
            for (int dj = 0; dj < 4; ++dj) {
                bf16x8 vb = *(const bf16x8*)(Vbuf + ((dj * 16 + lr) * 8 + slot) * 8);
                o[dj] = __builtin_amdgcn_mfma_f32_16x16x32_bf16(vb, pb, o[dj], 0, 0, 0);
            }
        }
        __builtin_amdgcn_s_setprio(0);
        // no trailing barrier: next iteration's barrier covers the hazard
    }

    // epilogue: sum L over the 4 lane-groups sharing q; add zero-key (+1,
    // doubled if q>=1021) and OOB window slots (+coob); scale and store.
    Lown += __shfl_xor(Lown, 16);
    Lown += __shfl_xor(Lown, 32);
    const int coob = (qg < 3 ? 3 - qg : 0) + (qg > 1021 ? qg - 1021 : 0);
    const float inv = 1.0f / (Lown + (float)(coob + 1 + (qg >= 1021 ? 1 : 0)));

    const int t = qg * 4 + r;
    float* orow = out + ((size_t)b * LSEQ + t) * DMODEL + h * DHEAD;
    #pragma unroll
    for (int dj = 0; dj < 4; ++dj) {
        float4 v = { o[dj][0] * inv, o[dj][1] * inv, o[dj][2] * inv, o[dj][3] * inv };
        *(float4*)(orow + dj * 16 + lh * 4) = v;
    }
}

extern "C" void kernel_launch(void* const* d_in, const int* in_sizes, int n_in,
                              void* d_out, int out_size, void* d_ws, size_t ws_size,
                              hipStream_t stream) {
    const float* x  = (const float*)d_in[0];
    const float* Wq = (const float*)d_in[1];
    const float* Wk = (const float*)d_in[2];
    const float* Wv = (const float*)d_in[3];
    float* out = (float*)d_out;

    const size_t SZ = (size_t)BATCH * NH * 4 * NPAD * DHEAD;   // per-tensor elems
    u16* Qb = (u16*)d_ws;
    u16* Kb = Qb + SZ;
    u16* Vb = Kb + SZ;

    // scratch for bf16 x and transposed W lives in d_out (overwritten by attn)
    u16* xb = (u16*)d_out;                       // 8192*512 u16
    u16* Wt = xb + (size_t)8192 * 512;           // 1536*512 u16

    prep_kernel<<<2240, 256, 0, stream>>>(x, Wq, Wk, Wv, xb, Wt);

    gemm_kernel<<<768, 256, 0, stream>>>(xb, Wt, Qb, Kb, Vb);

    dim3 ga(64, 8);
    attn_kernel<<<ga, 512, 0, stream>>>(Qb, Kb, Vb, out);
}

// Round 13
// 65.410 us; speedup vs baseline: 1.5187x; 1.0548x over previous
//
#include <hip/hip_runtime.h>
#include <hip/hip_bf16.h>

// Sparse self-attention == dense attention within each residue class (mod 4)
// + 7-wide window (duplicate entries => logit += 1.0 in log2 space)
// + OOB window slots adding exp2(0)=1 to the denominator
// + zero key n=1024 folded into the epilogue denominator.
// prep (x->bf16, W transpose) -> fused QKV GEMM (XCD-chunked) -> flash attn
// (R6 compute body + triple-buffered K/V staging with ONE barrier per tile).

#define BATCH 2
#define LSEQ  4096
#define DMODEL 512
#define NH    8
#define DHEAD 64
#define NPAD  1088      // K/V row stride (valid rows 0..1023; tails never touched)
#define QSCALE 0.18033688011112042f   // 0.125 * log2(e)

typedef __bf16 bf16x8 __attribute__((ext_vector_type(8)));
typedef __attribute__((ext_vector_type(4))) float f32x4;
typedef unsigned short u16;
typedef unsigned int u32;
typedef __attribute__((ext_vector_type(8))) u16 u16x8;
typedef __attribute__((ext_vector_type(4))) u16 u16x4;

__device__ __forceinline__ u16 f2bf(float f) {
    u32 u = __float_as_uint(f);
    u += 0x7fffu + ((u >> 16) & 1u);   // RNE, finite inputs
    return (u16)(u >> 16);
}

__device__ __forceinline__ u16 cvt_bf(float f) {
    __bf16 t = (__bf16)f;              // native v_cvt on gfx950
    return *(const u16*)&t;
}

__device__ __forceinline__ void gload16(const u16* g, u16* l) {
    __builtin_amdgcn_global_load_lds(
        (const __attribute__((address_space(1))) u32*)(const void*)g,
        (__attribute__((address_space(3))) u32*)(void*)l, 16, 0, 0);
}

// ---------------------------------------------------------------------------
// prep: bid<2048: xb = bf16(x);  2048..2239: Wt[c][k] = bf16(W[k][c]) transposed
// ---------------------------------------------------------------------------
__global__ __launch_bounds__(256) void prep_kernel(
    const float* __restrict__ x,
    const float* __restrict__ Wq, const float* __restrict__ Wk, const float* __restrict__ Wv,
    u16* __restrict__ xb, u16* __restrict__ Wt)
{
    const int bid = blockIdx.x, tid = threadIdx.x;
    if (bid < 2048) {
        const size_t i0 = (size_t)bid * 2048 + (size_t)tid * 8;
        float4 a = *(const float4*)(x + i0);
        float4 b = *(const float4*)(x + i0 + 4);
        u16x8 o = { f2bf(a.x), f2bf(a.y), f2bf(a.z), f2bf(a.w),
                    f2bf(b.x), f2bf(b.y), f2bf(b.z), f2bf(b.w) };
        *(u16x8*)(xb + i0) = o;
    } else {
        const int wb  = bid - 2048;            // 0..191
        const int mat = wb >> 6;
        const int t   = wb & 63;
        const int k0  = (t >> 3) * 64, c0 = (t & 7) * 64;
        const float* W = (mat == 0) ? Wq : (mat == 1) ? Wk : Wv;
        __shared__ u16 Ws[64][72];             // [k][c]
        #pragma unroll
        for (int i = 0; i < 4; ++i) {
            const int chunk = i * 256 + tid;
            const int kr = chunk >> 4, c4 = (chunk & 15) * 4;
            float4 v = *(const float4*)(W + (size_t)(k0 + kr) * DMODEL + c0 + c4);
            u16x4 q = { f2bf(v.x), f2bf(v.y), f2bf(v.z), f2bf(v.w) };
            *(u16x4*)&Ws[kr][c4] = q;
        }
        __syncthreads();
        const int cc = tid >> 2, kq = (tid & 3) * 16;
        alignas(16) u16 tmp[16];
        #pragma unroll
        for (int kk = 0; kk < 16; ++kk) tmp[kk] = Ws[kq + kk][cc];
        u16* dst = Wt + (size_t)(mat * 512 + c0 + cc) * DMODEL + k0 + kq;
        *(u16x8*)dst       = *(const u16x8*)&tmp[0];
        *(u16x8*)(dst + 8) = *(const u16x8*)&tmp[8];
    }
}

// ---------------------------------------------------------------------------
// Fused QKV GEMM: C = xb(8192x512) * Wt^T(512x1536), BM=BN=128, BK=64, 4 waves.
// 1-D grid, XCD-chunked. nt 0-3 -> Q (scaled), 4-7 -> K, 8-11 -> V^T.  [R6]
// ---------------------------------------------------------------------------
__global__ __launch_bounds__(256) void gemm_kernel(
    const u16* __restrict__ xb, const u16* __restrict__ Wt,
    u16* __restrict__ Qb, u16* __restrict__ Kb, u16* __restrict__ Vb)
{
    const int bid = blockIdx.x;
    const int xcd = bid & 7;
    const int j   = bid >> 3;            // 0..95
    const int mt  = xcd * 8 + (j / 12);  // 0..63
    const int nt  = j % 12;
    const int m0 = mt * 128;
    const int n0 = nt * 128;
    const int tid = threadIdx.x;
    const int w = tid >> 6, l = tid & 63, lr = l & 15, lh = l >> 4;
    const int wr = w >> 1, wc = w & 1;

    __shared__ u16 smem[16896];     // A:[0,8192) B:[8192,16384); V-retile 128*132
    u16* As = smem;
    u16* Bs = smem + 8192;

    f32x4 acc[4][4];
    const f32x4 fzero = {0.f, 0.f, 0.f, 0.f};
    #pragma unroll
    for (int mi = 0; mi < 4; ++mi)
        #pragma unroll
        for (int nj = 0; nj < 4; ++nj) acc[mi][nj] = fzero;

    for (int kt = 0; kt < 8; ++kt) {
        const int k0 = kt * 64;
        #pragma unroll
        for (int i = 0; i < 4; ++i) {
            const int cid = i * 256 + tid;
            const int row = cid >> 3, ch = cid & 7;
            const int sch = ch ^ (row & 7);
            u16* dstA = As + (i * 256 + w * 64) * 8;   // wave-uniform base
            u16* dstB = Bs + (i * 256 + w * 64) * 8;
            gload16(xb + (size_t)(m0 + row) * DMODEL + k0 + sch * 8, dstA);
            gload16(Wt + (size_t)(n0 + row) * DMODEL + k0 + sch * 8, dstB);
        }
        __syncthreads();

        #pragma unroll
        for (int kk = 0; kk < 2; ++kk) {
            const int cs = (kk * 4 + lh) ^ (lr & 7);   // swizzled chunk
            bf16x8 af[4], bfr[4];
            #pragma unroll
            for (int mi = 0; mi < 4; ++mi)
                af[mi] = *(const bf16x8*)(As + (wr * 64 + mi * 16 + lr) * 64 + cs * 8);
            #pragma unroll
            for (int nj = 0; nj < 4; ++nj)
                bfr[nj] = *(const bf16x8*)(Bs + (wc * 64 + nj * 16 + lr) * 64 + cs * 8);
            #pragma unroll
            for (int mi = 0; mi < 4; ++mi)
                #pragma unroll
                for (int nj = 0; nj < 4; ++nj)
                    acc[mi][nj] = __builtin_amdgcn_mfma_f32_16x16x32_bf16(af[mi], bfr[nj], acc[mi][nj], 0, 0, 0);
        }
        __syncthreads();
    }

    const int mat = nt >> 2;
    const int hp  = nt & 3;
    if (mat < 2) {
        u16* Ob = (mat == 0) ? Qb : Kb;
        const float osc = (mat == 0) ? QSCALE : 1.0f;
        #pragma unroll
        for (int mi = 0; mi < 4; ++mi) {
            const int gmb = m0 + wr * 64 + mi * 16 + lh * 4;
            const int b = gmb >> 12;
            #pragma unroll
            for (int rr = 0; rr < 4; ++rr) {
                const int t = (gmb + rr) & 4095;
                const int n = t >> 2, r = t & 3;
                #pragma unroll
                for (int nj = 0; nj < 4; ++nj) {
                    const int c  = wc * 64 + nj * 16 + lr;
                    const int h  = hp * 2 + (c >> 6);
                    const int dk = c & 63;
                    const size_t g = ((size_t)(b * NH + h)) * 4 + r;
                    Ob[(g * NPAD + n) * DHEAD + dk] = f2bf(acc[mi][nj][rr] * osc);
                }
            }
        }
    } else {
        // V: retile via LDS -> coalesced stores of V^T [g][dv][n]
        #pragma unroll
        for (int mi = 0; mi < 4; ++mi) {
            const int nrel = wr * 16 + mi * 4 + lh;
            #pragma unroll
            for (int nj = 0; nj < 4; ++nj) {
                const int c = wc * 64 + nj * 16 + lr;
                #pragma unroll
                for (int rr = 0; rr < 4; ++rr)
                    smem[c * 132 + rr * 32 + nrel] = f2bf(acc[mi][nj][rr]);
            }
        }
        __syncthreads();
        const int b  = m0 >> 12;
        const int nb = (m0 & 4095) >> 2;
        #pragma unroll
        for (int e = 0; e < 2; ++e) {
            const int chunk = e * 256 + tid;
            const int c = chunk & 127, r = chunk >> 7;
            const int h  = hp * 2 + (c >> 6);
            const int dv = c & 63;
            const size_t g = ((size_t)(b * NH + h)) * 4 + r;
            u16* dst = Vb + (g * DHEAD + dv) * NPAD + nb;
            const u16* src = smem + c * 132 + r * 32;
            alignas(16) u16 tmp[32];
            #pragma unroll
            for (int q8 = 0; q8 < 8; ++q8)
                *(u16x4*)&tmp[q8 * 4] = *(const u16x4*)(src + q8 * 4);
            #pragma unroll
            for (int q16 = 0; q16 < 4; ++q16)
                *(u16x8*)(dst + q16 * 8) = *(const u16x8*)&tmp[q16 * 8];
        }
    }
}

// ---------------------------------------------------------------------------
// Flash attention per (b,h,r): 128 queries/block (8 waves x 16 rows),
// 16 key tiles of 64. R6 compute body; TRIPLE-buffered K/V, ONE barrier/tile,
// prefetch issued after the barrier (WAR-safe: barrier t separates reads of
// buf (t-1)%3 from the write of tile t+2 into the same buffer).
// ---------------------------------------------------------------------------
__global__ __launch_bounds__(512) void attn_kernel(
    const u16* __restrict__ Qb, const u16* __restrict__ Kb, const u16* __restrict__ Vb,
    float* __restrict__ out)
{
    const int g  = blockIdx.x;          // ((b*8+h)*4+r): blocks sharing g -> same XCD
    const int b  = g >> 5;
    const int h  = (g >> 2) & 7;
    const int r  = g & 3;
    const int q0 = blockIdx.y * 128;
    const int tid = threadIdx.x;
    const int w  = tid >> 6;            // 0..7
    const int l  = tid & 63;
    const int lr = l & 15, lh = l >> 4;

    const u16* Qg  = Qb + (size_t)g * NPAD * DHEAD;
    const u16* Kg  = Kb + (size_t)g * NPAD * DHEAD;
    const u16* Vtg = Vb + (size_t)g * DHEAD * NPAD;   // [dv][n]

    __shared__ u16 KV[3][2][4096];   // [buf][K/V][64 rows][8 slots][8 u16]
    __shared__ u16 Ps[8][16][68];    // per-wave P tile [qrow][m]

    // staging: thread -> (row = tid>>3, slot = tid&7), source chunk XOR-swizzled
    const int srow = tid >> 3;
    const int ssch = (tid & 7) ^ (srow & 7);
    const u16* ksrc0 = Kg  + (size_t)srow * DHEAD + ssch * 8;
    const u16* vsrc0 = Vtg + (size_t)srow * NPAD  + ssch * 8;

    bf16x8 qa[2];
    {
        const u16* qrow = Qg + (size_t)(q0 + w * 16 + lr) * DHEAD;
        qa[0] = *(const bf16x8*)(qrow + lh * 8);
        qa[1] = *(const bf16x8*)(qrow + 32 + lh * 8);
    }

    const f32x4 fzero = {0.f, 0.f, 0.f, 0.f};
    f32x4 o[4];
    #pragma unroll
    for (int j = 0; j < 4; ++j) o[j] = fzero;
    float Lpart[4] = {0.f, 0.f, 0.f, 0.f};

    const int qw0 = q0 + w * 16;

    // prologue: stage tiles 0,1 into bufs 0,1
    gload16(ksrc0,              &KV[0][0][w * 512]);
    gload16(vsrc0,              &KV[0][1][w * 512]);
    gload16(ksrc0 + 64 * DHEAD, &KV[1][0][w * 512]);
    gload16(vsrc0 + 64,         &KV[1][1][w * 512]);

    for (int mt = 0; mt < 16; ++mt) {
        if (mt < 15) asm volatile("s_waitcnt vmcnt(2)" ::: "memory");
        else         asm volatile("s_waitcnt vmcnt(0)" ::: "memory");
        __builtin_amdgcn_s_barrier();
        // issue tile mt+2 AFTER the barrier (WAR-safe vs readers of tile mt-1)
        if (mt < 14) {
            const int nb = (mt + 2) % 3;
            gload16(ksrc0 + (size_t)(mt + 2) * 64 * DHEAD, &KV[nb][0][w * 512]);
            gload16(vsrc0 + (mt + 2) * 64,                 &KV[nb][1][w * 512]);
        }

        const u16* Kbuf = KV[mt % 3][0];
        const u16* Vbuf = KV[mt % 3][1];

        // S = Q K^T (wave: 16 x 64), logits already in log2 space
        f32x4 s[4];
        __builtin_amdgcn_s_setprio(1);
        #pragma unroll
        for (int ni = 0; ni < 4; ++ni) {
            const int rbase = (ni * 16 + lr) * 8;
            const int sl0 = lh ^ (lr & 7), sl1 = (4 + lh) ^ (lr & 7);
            bf16x8 kb0 = *(const bf16x8*)(Kbuf + (rbase + sl0) * 8);
            bf16x8 kb1 = *(const bf16x8*)(Kbuf + (rbase + sl1) * 8);
            f32x4 t = __builtin_amdgcn_mfma_f32_16x16x32_bf16(qa[0], kb0, fzero, 0, 0, 0);
            s[ni] = __builtin_amdgcn_mfma_f32_16x16x32_bf16(qa[1], kb1, t, 0, 0, 0);
        }
        __builtin_amdgcn_s_setprio(0);

        const int m0 = mt * 64;
        const bool special = (m0 + 66 >= qw0) && (m0 <= qw0 + 18);
        if (!special) {
            #pragma unroll
            for (int ni = 0; ni < 4; ++ni) {
                #pragma unroll
                for (int rr = 0; rr < 4; ++rr) {
                    const float p = __builtin_amdgcn_exp2f(s[ni][rr]);
                    Lpart[rr] += p;
                    Ps[w][lh * 4 + rr][ni * 16 + lr] = cvt_bf(p);
                }
            }
        } else {
            #pragma unroll
            for (int ni = 0; ni < 4; ++ni) {
                const int mg = m0 + ni * 16 + lr;
                #pragma unroll
                for (int rr = 0; rr < 4; ++rr) {
                    const int qg = qw0 + lh * 4 + rr;
                    float v = s[ni][rr];
                    const int dd = mg - qg;
                    if (dd >= -3 && dd <= 3) v += 1.0f;    // window doubling
                    const float p = __builtin_amdgcn_exp2f(v);
                    Lpart[rr] += p;
                    Ps[w][lh * 4 + rr][ni * 16 + lr] = cvt_bf(p);
                }
            }
        }

        // O += P V (Ps per-wave: intra-wave lgkmcnt ordering only)
        __builtin_amdgcn_s_setprio(1);
        #pragma unroll
        for (int kk = 0; kk < 2; ++kk) {
            const int slot = (kk * 4 + lh) ^ (lr & 7);
            bf16x8 pa = *(const bf16x8*)&Ps[w][lr][kk * 32 + lh * 8];
            #pragma unroll
            for (int j = 0; j < 4; ++j) {
                bf16x8 vb = *(const bf16x8*)(Vbuf + ((j * 16 + lr) * 8 + slot) * 8);
                o[j] = __builtin_amdgcn_mfma_f32_16x16x32_bf16(pa, vb, o[j], 0, 0, 0);
            }
        }
        __builtin_amdgcn_s_setprio(0);
        // no trailing barrier: next iteration's barrier covers the WAR hazard
    }

    // epilogue: dense zero-key (+1), its window double (q>=1021 ? +1), OOB (+coob)
    #pragma unroll
    for (int rr = 0; rr < 4; ++rr) {
        float s_ = Lpart[rr];
        #pragma unroll
        for (int off = 1; off < 16; off <<= 1)
            s_ += __shfl_xor(s_, off, 16);
        const int qg = qw0 + lh * 4 + rr;
        const int coob = (qg < 3 ? 3 - qg : 0) + (qg > 1021 ? qg - 1021 : 0);
        const float extra = (float)(coob + 1 + (qg >= 1021 ? 1 : 0));
        const float inv = 1.0f / (s_ + extra);
        const int t = qg * 4 + r;
        float* orow = out + ((size_t)b * LSEQ + t) * DMODEL + h * DHEAD;
        #pragma unroll
        for (int j = 0; j < 4; ++j)
            orow[j * 16 + lr] = o[j][rr] * inv;
    }
}

extern "C" void kernel_launch(void* const* d_in, const int* in_sizes, int n_in,
                              void* d_out, int out_size, void* d_ws, size_t ws_size,
                              hipStream_t stream) {
    const float* x  = (const float*)d_in[0];
    const float* Wq = (const float*)d_in[1];
    const float* Wk = (const float*)d_in[2];
    const float* Wv = (const float*)d_in[3];
    float* out = (float*)d_out;

    const size_t SZ = (size_t)BATCH * NH * 4 * NPAD * DHEAD;   // per-tensor elems
    u16* Qb = (u16*)d_ws;
    u16* Kb = Qb + SZ;
    u16* Vb = Kb + SZ;

    // scratch for bf16 x and transposed W lives in d_out (overwritten by attn)
    u16* xb = (u16*)d_out;                       // 8192*512 u16
    u16* Wt = xb + (size_t)8192 * 512;           // 1536*512 u16

    prep_kernel<<<2240, 256, 0, stream>>>(x, Wq, Wk, Wv, xb, Wt);

    gemm_kernel<<<768, 256, 0, stream>>>(xb, Wt, Qb, Kb, Vb);

    dim3 ga(64, 8);
    attn_kernel<<<ga, 512, 0, stream>>>(Qb, Kb, Vb, out);
}